// Round 9
// baseline (348.972 us; speedup 1.0000x reference)
//
#include <hip/hip_runtime.h>
#include <stdint.h>

typedef unsigned short u16;
typedef unsigned int u32;
typedef __bf16 bf16x8 __attribute__((ext_vector_type(8)));
typedef __bf16 bf16x4 __attribute__((ext_vector_type(4)));
typedef float f32x4 __attribute__((ext_vector_type(4)));

__device__ __forceinline__ float bf2f(u16 u) {
  union { unsigned int i; float f; } v; v.i = ((unsigned int)u) << 16; return v.f;
}
__device__ __forceinline__ u16 f2bf(float f) {
  union { float f; unsigned int i; } v; v.f = f;
  unsigned int r = v.i + 0x7fffu + ((v.i >> 16) & 1u);
  return (u16)(r >> 16);
}
// raw v_exp_f32 (2^x): bounded args here, 1-ulp is plenty for bf16 P-values.
__device__ __forceinline__ float fastexp2(float x) {
  float r; asm("v_exp_f32 %0, %1" : "=v"(r) : "v"(x)); return r;
}
// async global->LDS, 16B per lane. LDS dest is wave-uniform base + lane*16.
__device__ __forceinline__ void ld16(const void* g, void* l) {
  __builtin_amdgcn_global_load_lds(
      (const __attribute__((address_space(1))) unsigned int*)g,
      (__attribute__((address_space(3))) unsigned int*)l, 16, 0, 0);
}

// fp32 -> bf16 cast of x + 5 weight matrices, one launch.
__global__ __launch_bounds__(256) void k_cast(
    const float* __restrict__ s0, u16* __restrict__ d0,
    const float* __restrict__ s1, u16* __restrict__ d1,
    const float* __restrict__ s2, u16* __restrict__ d2,
    const float* __restrict__ s3, u16* __restrict__ d3,
    const float* __restrict__ s4, u16* __restrict__ d4,
    const float* __restrict__ s5, u16* __restrict__ d5)
{
  int b = blockIdx.x;
  const float* s; u16* d;
  if (b < 4096)       { s = s0; d = d0; }
  else if (b < 8192)  { s = s1; d = d1; b -= 4096; }
  else if (b < 9216)  { s = s2; d = d2; b -= 8192; }
  else if (b < 10240) { s = s3; d = d3; b -= 9216; }
  else if (b < 14336) { s = s4; d = d4; b -= 10240; }
  else                { s = s5; d = d5; b -= 14336; }
  const int i = (b * 256 + threadIdx.x) * 4;
  const float4 v = *(const float4*)(s + i);
  ushort4 o;
  o.x = f2bf(v.x); o.y = f2bf(v.y); o.z = f2bf(v.z); o.w = f2bf(v.w);
  *(ushort4*)(d + i) = o;
}

// ---- qkvg GEMM with FUSED RoPE+RMSNorm epilogue.
// __launch_bounds__(256,5): occupancy is LDS-bound at 5 blocks/CU (32 KB), so
// cap VGPR at 102 (main loop fits in 84 -- R7 measurement; any cap-forced
// spill lands in the once-per-block epilogue where it's free). Epilogue keeps
// live state minimal: no precomputed weight/index arrays.
__global__ __launch_bounds__(256, 5) void k_gemm_qkvg(
    const u16* __restrict__ x, const u16* __restrict__ wq, const u16* __restrict__ wk,
    const u16* __restrict__ wv, const u16* __restrict__ wg,
    const float* __restrict__ cosp, const float* __restrict__ sinp,
    const float* __restrict__ qn, const float* __restrict__ kn,
    u16* __restrict__ out)
{
  __shared__ __align__(16) u16 As[128 * 64];
  __shared__ __align__(16) u16 Bs[128 * 64];
  const int m0 = blockIdx.x * 128;
  const int c0 = blockIdx.y * 128;
  const u16* B; int br;
  if (c0 < 2048)      { B = wq; br = c0; }
  else if (c0 < 2560) { B = wk; br = c0 - 2048; }
  else if (c0 < 3072) { B = wv; br = c0 - 2560; }
  else                { B = wg; br = c0 - 3072; }
  const u16* A = x + (size_t)m0 * 2048;
  const int lda = 2048, ldb = 2048, K = 2048;

  const int tid = threadIdx.x;
  const int wave = tid >> 6, lane = tid & 63;
  const int wrow = (wave >> 1) * 64, wcol = (wave & 1) * 64;
  const int fr = lane & 15, kg = lane >> 4;
  const int srl = lane >> 3;
  const int scg = (lane & 7) ^ srl;

  f32x4 acc[4][4];
  const f32x4 z = {0.f, 0.f, 0.f, 0.f};
  for (int i = 0; i < 4; i++) for (int j = 0; j < 4; j++) acc[i][j] = z;

  const u16* Ag = A + (size_t)(wave * 8 + srl) * lda + scg * 8;
  const u16* Bg = B + (size_t)(br + wave * 8 + srl) * ldb + scg * 8;
  u16* Asw = As + wave * 8 * 64;
  u16* Bsw = Bs + wave * 8 * 64;
  const int sxr = fr & 7;

  for (int k0 = 0; k0 < K; k0 += 64) {
    for (int i = 0; i < 4; i++) {
      ld16(Ag + k0 + (size_t)(i * 32) * lda, Asw + i * 32 * 64);
      ld16(Bg + k0 + (size_t)(i * 32) * ldb, Bsw + i * 32 * 64);
    }
    __syncthreads();
    bf16x8 af[4][2], bfr[4][2];
    for (int i = 0; i < 4; i++)
      for (int h = 0; h < 2; h++) {
        af[i][h]  = *(const bf16x8*)&As[(wrow + i * 16 + fr) * 64 + (((h * 4 + kg) ^ sxr)) * 8];
        bfr[i][h] = *(const bf16x8*)&Bs[(wcol + i * 16 + fr) * 64 + (((h * 4 + kg) ^ sxr)) * 8];
      }
    for (int h = 0; h < 2; h++)
      for (int mi = 0; mi < 4; mi++)
        for (int ni = 0; ni < 4; ni++)
          acc[mi][ni] = __builtin_amdgcn_mfma_f32_16x16x32_bf16(af[mi][h], bfr[ni][h], acc[mi][ni], 0, 0, 0);
    __syncthreads();
  }

  const int er = kg * 4, ec = fr;
  const int head_col0 = c0 + wcol;           // wave-uniform; one head per wave-half
  u16* Cw = out + (size_t)m0 * 5120 + c0;

  if (head_col0 < 2560) {
    // q (head_col0<2048, weights qn) or k (else, weights kn)
    const float* wn = (head_col0 < 2048) ? qn : kn;
    const bool odd = (fr & 1);
#pragma unroll
    for (int mi = 0; mi < 4; mi++)
#pragma unroll
      for (int r = 0; r < 4; r++) {
        const int s = m0 + wrow + mi * 16 + er + r;
        const float* crow = cosp + s * 32;
        const float* srow = sinp + s * 32;
        float o[4], ss = 0.f;
#pragma unroll
        for (int ni = 0; ni < 4; ni++) {
          const int jj = (ni * 16 + fr) >> 1;
          const float v = acc[mi][ni][r];
          const float pv = __shfl_xor(v, 1, 64);     // partner col of the RoPE pair
          const float cc = crow[jj];
          const float sn = srow[jj];
          const float ov = odd ? fmaf(pv, sn, v * cc)       // odd col: xr=pv, xi=v
                               : fmaf(v, cc, -(pv * sn));   // even col: xr=v, xi=pv
          o[ni] = ov;
          ss += ov * ov;
        }
        ss += __shfl_xor(ss, 1, 64);
        ss += __shfl_xor(ss, 2, 64);
        ss += __shfl_xor(ss, 4, 64);
        ss += __shfl_xor(ss, 8, 64);                 // sum over 64 head cols
        const float inv = rsqrtf(ss * (1.0f / 64.0f) + 1e-6f);
#pragma unroll
        for (int ni = 0; ni < 4; ni++)
          Cw[(size_t)(wrow + mi * 16 + er + r) * 5120 + wcol + ni * 16 + ec] =
              f2bf(o[ni] * inv * wn[ni * 16 + fr]);
      }
  } else {
#pragma unroll
    for (int mi = 0; mi < 4; mi++)
#pragma unroll
      for (int ni = 0; ni < 4; ni++)
#pragma unroll
        for (int r = 0; r < 4; r++)
          Cw[(size_t)(wrow + mi * 16 + er + r) * 5120 + wcol + ni * 16 + ec] =
              f2bf(acc[mi][ni][r]);
  }
}

// 128(m) x 64(n) tile GEMM for the output projection: 512 blocks -> 2/CU.
__global__ __launch_bounds__(256) void k_gemm_out(
    const u16* __restrict__ a, const u16* __restrict__ wo, float* __restrict__ out)
{
  __shared__ __align__(16) u16 As[128 * 64];   // 16 KB
  __shared__ __align__(16) u16 Bs[64 * 64];    //  8 KB
  const int m0 = blockIdx.x * 128;
  const int c0 = blockIdx.y * 64;
  const int lda = 2048, ldb = 2048, ldc = 2048, K = 2048;
  const u16* A = a  + (size_t)m0 * lda;
  const u16* B = wo + (size_t)c0 * ldb;
  float* C = out + (size_t)m0 * ldc + c0;

  const int tid = threadIdx.x;
  const int wave = tid >> 6, lane = tid & 63;
  const int wrow = (wave >> 1) * 64, wcol = (wave & 1) * 32;
  const int fr = lane & 15, kg = lane >> 4;
  const int srl = lane >> 3;
  const int scg = (lane & 7) ^ srl;

  f32x4 acc[4][2];
  const f32x4 z = {0.f, 0.f, 0.f, 0.f};
  for (int i = 0; i < 4; i++) for (int j = 0; j < 2; j++) acc[i][j] = z;

  const u16* Ag = A + (size_t)(wave * 8 + srl) * lda + scg * 8;
  const u16* Bg = B + (size_t)(wave * 8 + srl) * ldb + scg * 8;
  u16* Asw = As + wave * 8 * 64;
  u16* Bsw = Bs + wave * 8 * 64;
  const int sxr = fr & 7;

  for (int k0 = 0; k0 < K; k0 += 64) {
#pragma unroll
    for (int i = 0; i < 4; i++)
      ld16(Ag + k0 + (size_t)(i * 32) * lda, Asw + i * 32 * 64);
#pragma unroll
    for (int i = 0; i < 2; i++)
      ld16(Bg + k0 + (size_t)(i * 32) * ldb, Bsw + i * 32 * 64);
    __syncthreads();
    bf16x8 af[4][2], bfr[2][2];
#pragma unroll
    for (int i = 0; i < 4; i++)
#pragma unroll
      for (int h = 0; h < 2; h++)
        af[i][h] = *(const bf16x8*)&As[(wrow + i * 16 + fr) * 64 + (((h * 4 + kg) ^ sxr)) * 8];
#pragma unroll
    for (int i = 0; i < 2; i++)
#pragma unroll
      for (int h = 0; h < 2; h++)
        bfr[i][h] = *(const bf16x8*)&Bs[(wcol + i * 16 + fr) * 64 + (((h * 4 + kg) ^ sxr)) * 8];
#pragma unroll
    for (int h = 0; h < 2; h++)
#pragma unroll
      for (int mi = 0; mi < 4; mi++)
#pragma unroll
        for (int ni = 0; ni < 2; ni++)
          acc[mi][ni] = __builtin_amdgcn_mfma_f32_16x16x32_bf16(af[mi][h], bfr[ni][h], acc[mi][ni], 0, 0, 0);
    __syncthreads();
  }
  const int er = kg * 4, ec = fr;
#pragma unroll
  for (int mi = 0; mi < 4; mi++)
#pragma unroll
    for (int ni = 0; ni < 2; ni++)
#pragma unroll
      for (int r = 0; r < 4; r++)
        C[(size_t)(wrow + mi * 16 + er + r) * ldc + wcol + ni * 16 + ec] = acc[mi][ni][r];
}

// V-transpose only (RoPE+RMSNorm fused into the qkvg epilogue):
// v[s][g*64+d] -> vt[(g*64+d)][s], LDS-tiled. 256 blocks.
__global__ __launch_bounds__(256) void k_prep(
    const u16* __restrict__ qkvg, u16* __restrict__ vt)
{
  __shared__ u16 Ls[64 * 72];
  const int bb = blockIdx.x;
  const int s0 = (bb & 31) * 64, g0 = (bb >> 5) * 64;
  const int tid = threadIdx.x;
  const int lr = tid >> 4, lc = (tid & 15) * 4;
  for (int p = 0; p < 4; p++) {
    const int r = p * 16 + lr;
    *(ushort4*)&Ls[r * 72 + lc] = *(const ushort4*)&qkvg[(size_t)(s0 + r) * 5120 + 2560 + g0 + lc];
  }
  __syncthreads();
  for (int p = 0; p < 4; p++) {
    const int r = p * 16 + lr;
    ushort4 o;
    o.x = Ls[(lc + 0) * 72 + r];
    o.y = Ls[(lc + 1) * 72 + r];
    o.z = Ls[(lc + 2) * 72 + r];
    o.w = Ls[(lc + 3) * 72 + r];
    *(ushort4*)&vt[(size_t)(g0 + r) * 2048 + s0 + lc] = o;
  }
}

// ---- Split-KV flash attention pass 1, fixed-max softmax, SWAPPED QK^T,
// 2 q-heads per block (48 KB LDS, 3 blocks/CU, single-buffer K/V).
__global__ __launch_bounds__(256, 3) void k_attn_part(
    const u16* __restrict__ qkvg, const u16* __restrict__ vt,
    u16* __restrict__ part, float* __restrict__ ml)
{
  __shared__ __align__(16) u16 SMEM[3 * 64 * 128];  // 48 KB
  u16* Ks = SMEM;               // [128 key][64 hd]  swizzled
  u16* Vs = SMEM + 8192;        // [64 hd][128 key]  swizzled
  u16* Ps = SMEM + 16384;       // [64 q][128 key]   swizzled
  const int c = blockIdx.x, gp = blockIdx.y;
  const int g = gp >> 1, h0 = (gp >> 1) * 4 + (gp & 1) * 2;   // heads h0, h0+1
  int qt, ci;
  if (c < 8)       { qt = c;                 ci = 0; }
  else if (c < 24) { qt = 8 + ((c - 8) >> 1);  ci = (c - 8) & 1; }
  else if (c < 48) { qt = 16 + (c - 24) / 3;   ci = (c - 24) % 3; }
  else             { qt = 24 + ((c - 48) >> 2); ci = (c - 48) & 3; }
  const int kb0 = ci * 512;
  const int kend = min(kb0 + 512, (qt + 1) * 64);
  const int q0 = qt * 64;
  const int tid = threadIdx.x, wave = tid >> 6, lane = tid & 63;
  const int fr = lane & 15, kg = lane >> 4;
  const int sx = fr & 7;

  // Stage the 64 x 128 Q slab (heads h0, h0+1 adjacent columns) through SMEM.
  {
    const u16* Qg = qkvg + (size_t)(q0 + wave * 16 + (lane >> 4)) * 5120 + h0 * 64 + (lane & 15) * 8;
#pragma unroll
    for (int i = 0; i < 4; i++)
      ld16(Qg + (size_t)(i * 4) * 5120, SMEM + (wave * 16 + i * 4) * 128);
  }
  __syncthreads();
  bf16x8 aq[2][2];
#pragma unroll
  for (int hh = 0; hh < 2; hh++)
#pragma unroll
    for (int hf = 0; hf < 2; hf++)
      aq[hh][hf] = *(const bf16x8*)&SMEM[(wave * 16 + fr) * 128 + hh * 64 + hf * 32 + kg * 8];
  __syncthreads();

  f32x4 o[2][4];
  const f32x4 z = {0.f, 0.f, 0.f, 0.f};
#pragma unroll
  for (int hh = 0; hh < 2; hh++)
#pragma unroll
    for (int i = 0; i < 4; i++) o[hh][i] = z;
  float L[2] = {0.f, 0.f};
  const int qrow = q0 + wave * 16 + fr;      // this lane's q-row (swapped layout)
  const int prow = wave * 16 + fr;           // P-tile row owned by this lane

  const int krl = wave * 8 + (lane >> 3);
  const int kcg = (lane & 7) ^ (krl & 7);
  const int vrl = wave * 4 + kg;
  const int vcg = fr ^ (vrl & 7);

  for (int kb = kb0; kb < kend; kb += 128) {
    {
      const u16* Kg = qkvg + (size_t)(kb + krl) * 5120 + 2048 + g * 64 + kcg * 8;
#pragma unroll
      for (int i = 0; i < 4; i++)
        ld16(Kg + (size_t)(i * 32) * 5120, Ks + (i * 32 + wave * 8) * 64);
    }
    {
      const u16* Vg = vt + (size_t)(g * 64 + vrl) * 2048 + kb + vcg * 8;
#pragma unroll
      for (int i = 0; i < 4; i++)
        ld16(Vg + (size_t)(i * 16) * 2048, Vs + (i * 16 + wave * 4) * 128);
    }
    __syncthreads();

    const bool masked = (kb + 127 > q0 + wave * 16);   // wave-uniform
    u32* Ps32 = (u32*)Ps;
    const int pb32 = prow * 64;

    // ---- QK for BOTH heads, sharing the K-fragment loads.
    f32x4 s0[8], s1[8];
#pragma unroll
    for (int i = 0; i < 8; i++) { s0[i] = z; s1[i] = z; }
    __builtin_amdgcn_s_setprio(1);
#pragma unroll
    for (int ni = 0; ni < 8; ni++) {
      const bf16x8 bk0 = *(const bf16x8*)&Ks[(ni * 16 + fr) * 64 + ((kg ^ sx)) * 8];
      const bf16x8 bk1 = *(const bf16x8*)&Ks[(ni * 16 + fr) * 64 + (((kg + 4) ^ sx)) * 8];
      s0[ni] = __builtin_amdgcn_mfma_f32_16x16x32_bf16(bk0, aq[0][0], s0[ni], 0, 0, 0);
      s0[ni] = __builtin_amdgcn_mfma_f32_16x16x32_bf16(bk1, aq[0][1], s0[ni], 0, 0, 0);
      s1[ni] = __builtin_amdgcn_mfma_f32_16x16x32_bf16(bk0, aq[1][0], s1[ni], 0, 0, 0);
      s1[ni] = __builtin_amdgcn_mfma_f32_16x16x32_bf16(bk1, aq[1][1], s1[ni], 0, 0, 0);
    }
    __builtin_amdgcn_s_setprio(0);

    // ---- head 0 softmax -> P-tile (one b64 store per ni)
    {
      float Lh = 0.f;
      if (masked) {
#pragma unroll
        for (int ni = 0; ni < 8; ni++) {
          const int dlim = qrow - (kb + ni * 16 + kg * 4);
          float p0 = fastexp2(fmaf(s0[ni][0], 0.18033688f, -11.5415603f));
          float p1 = fastexp2(fmaf(s0[ni][1], 0.18033688f, -11.5415603f));
          float p2 = fastexp2(fmaf(s0[ni][2], 0.18033688f, -11.5415603f));
          float p3 = fastexp2(fmaf(s0[ni][3], 0.18033688f, -11.5415603f));
          p0 = (0 <= dlim) ? p0 : 0.f;
          p1 = (1 <= dlim) ? p1 : 0.f;
          p2 = (2 <= dlim) ? p2 : 0.f;
          p3 = (3 <= dlim) ? p3 : 0.f;
          Lh += (p0 + p1) + (p2 + p3);
          bf16x4 w;
          w[0] = (__bf16)p0; w[1] = (__bf16)p1; w[2] = (__bf16)p2; w[3] = (__bf16)p3;
          *(bf16x4*)&Ps32[pb32 + ((2 * ni + (kg >> 1)) ^ sx) * 4 + (kg & 1) * 2] = w;
        }
      } else {
#pragma unroll
        for (int ni = 0; ni < 8; ni++) {
          float p0 = fastexp2(fmaf(s0[ni][0], 0.18033688f, -11.5415603f));
          float p1 = fastexp2(fmaf(s0[ni][1], 0.18033688f, -11.5415603f));
          float p2 = fastexp2(fmaf(s0[ni][2], 0.18033688f, -11.5415603f));
          float p3 = fastexp2(fmaf(s0[ni][3], 0.18033688f, -11.5415603f));
          Lh += (p0 + p1) + (p2 + p3);
          bf16x4 w;
          w[0] = (__bf16)p0; w[1] = (__bf16)p1; w[2] = (__bf16)p2; w[3] = (__bf16)p3;
          *(bf16x4*)&Ps32[pb32 + ((2 * ni + (kg >> 1)) ^ sx) * 4 + (kg & 1) * 2] = w;
        }
      }
      L[0] += Lh;
    }
    // ---- head 0 PV (in-wave produce/consume of wave-private P rows)
    __builtin_amdgcn_s_setprio(1);
#pragma unroll
    for (int k0 = 0; k0 < 128; k0 += 32) {
      const bf16x8 ap = *(const bf16x8*)&Ps[prow * 128 + ((((k0 >> 3) + kg)) ^ sx) * 8];
#pragma unroll
      for (int ni = 0; ni < 4; ni++) {
        const bf16x8 bv = *(const bf16x8*)&Vs[(ni * 16 + fr) * 128 + (((k0 >> 3) + kg) ^ sx) * 8];
        o[0][ni] = __builtin_amdgcn_mfma_f32_16x16x32_bf16(ap, bv, o[0][ni], 0, 0, 0);
      }
    }
    __builtin_amdgcn_s_setprio(0);

    // ---- head 1 softmax (VALU; overlaps PV0's MFMA) -> P-tile overwrite
    {
      float Lh = 0.f;
      if (masked) {
#pragma unroll
        for (int ni = 0; ni < 8; ni++) {
          const int dlim = qrow - (kb + ni * 16 + kg * 4);
          float p0 = fastexp2(fmaf(s1[ni][0], 0.18033688f, -11.5415603f));
          float p1 = fastexp2(fmaf(s1[ni][1], 0.18033688f, -11.5415603f));
          float p2 = fastexp2(fmaf(s1[ni][2], 0.18033688f, -11.5415603f));
          float p3 = fastexp2(fmaf(s1[ni][3], 0.18033688f, -11.5415603f));
          p0 = (0 <= dlim) ? p0 : 0.f;
          p1 = (1 <= dlim) ? p1 : 0.f;
          p2 = (2 <= dlim) ? p2 : 0.f;
          p3 = (3 <= dlim) ? p3 : 0.f;
          Lh += (p0 + p1) + (p2 + p3);
          bf16x4 w;
          w[0] = (__bf16)p0; w[1] = (__bf16)p1; w[2] = (__bf16)p2; w[3] = (__bf16)p3;
          *(bf16x4*)&Ps32[pb32 + ((2 * ni + (kg >> 1)) ^ sx) * 4 + (kg & 1) * 2] = w;
        }
      } else {
#pragma unroll
        for (int ni = 0; ni < 8; ni++) {
          float p0 = fastexp2(fmaf(s1[ni][0], 0.18033688f, -11.5415603f));
          float p1 = fastexp2(fmaf(s1[ni][1], 0.18033688f, -11.5415603f));
          float p2 = fastexp2(fmaf(s1[ni][2], 0.18033688f, -11.5415603f));
          float p3 = fastexp2(fmaf(s1[ni][3], 0.18033688f, -11.5415603f));
          Lh += (p0 + p1) + (p2 + p3);
          bf16x4 w;
          w[0] = (__bf16)p0; w[1] = (__bf16)p1; w[2] = (__bf16)p2; w[3] = (__bf16)p3;
          *(bf16x4*)&Ps32[pb32 + ((2 * ni + (kg >> 1)) ^ sx) * 4 + (kg & 1) * 2] = w;
        }
      }
      L[1] += Lh;
    }
    // ---- head 1 PV
    __builtin_amdgcn_s_setprio(1);
#pragma unroll
    for (int k0 = 0; k0 < 128; k0 += 32) {
      const bf16x8 ap = *(const bf16x8*)&Ps[prow * 128 + ((((k0 >> 3) + kg)) ^ sx) * 8];
#pragma unroll
      for (int ni = 0; ni < 4; ni++) {
        const bf16x8 bv = *(const bf16x8*)&Vs[(ni * 16 + fr) * 128 + (((k0 >> 3) + kg) ^ sx) * 8];
        o[1][ni] = __builtin_amdgcn_mfma_f32_16x16x32_bf16(ap, bv, o[1][ni], 0, 0, 0);
      }
    }
    __builtin_amdgcn_s_setprio(0);
    __syncthreads();                         // Ks/Vs/Ps reads done before next stage
  }

#pragma unroll
  for (int hh = 0; hh < 2; hh++) {
    float Lh = L[hh];
    Lh += __shfl_xor(Lh, 16, 64);
    Lh += __shfl_xor(Lh, 32, 64);
    const int h = h0 + hh;
    const int pbase = (h * 80 + c) * 4096;
#pragma unroll
    for (int ni = 0; ni < 4; ni++)
#pragma unroll
      for (int r = 0; r < 4; r++)
        part[pbase + (wave * 16 + kg * 4 + r) * 64 + ni * 16 + fr] = f2bf(o[hh][ni][r]);
    if (lane < 16) ml[(h * 80 + c) * 64 + wave * 16 + fr] = Lh;
  }
}

// ---- Split-KV pass 2: plain sums (shared fixed max); fuse sigmoid gating.
// Vectorized: each thread owns 4 cols (ushort4) x 4 rows -> 8 B/lane memory ops.
__global__ __launch_bounds__(256) void k_attn_comb(
    const u16* __restrict__ part, const float* __restrict__ ml,
    const u16* __restrict__ qkvg, u16* __restrict__ aout)
{
  const int qt = blockIdx.x, h = blockIdx.y;
  int cb, nch;
  if (qt < 8)       { cb = qt;               nch = 1; }
  else if (qt < 16) { cb = 8 + 2 * (qt - 8);  nch = 2; }
  else if (qt < 24) { cb = 24 + 3 * (qt - 16); nch = 3; }
  else              { cb = 48 + 4 * (qt - 24); nch = 4; }
  const int c4 = (threadIdx.x & 15) * 4;     // column base within the head
  const int rg = threadIdx.x >> 4;           // 0..15
  const float LOG2E = 1.44269504f;
#pragma unroll
  for (int rr = 0; rr < 4; rr++) {
    const int rl = rr * 16 + rg;
    const int row = qt * 64 + rl;
    float L = 0.f, o0 = 0.f, o1 = 0.f, o2 = 0.f, o3 = 0.f;
    for (int cc = 0; cc < nch; cc++) {
      L += ml[(h * 80 + cb + cc) * 64 + rl];
      const ushort4 pv = *(const ushort4*)&part[(size_t)(h * 80 + cb + cc) * 4096 + rl * 64 + c4];
      o0 += bf2f(pv.x); o1 += bf2f(pv.y); o2 += bf2f(pv.z); o3 += bf2f(pv.w);
    }
    const ushort4 gv = *(const ushort4*)&qkvg[(size_t)row * 5120 + 3072 + h * 64 + c4];
    const float inv = 1.0f / L;
    const float s0 = 1.0f / (1.0f + fastexp2(-bf2f(gv.x) * LOG2E));
    const float s1 = 1.0f / (1.0f + fastexp2(-bf2f(gv.y) * LOG2E));
    const float s2 = 1.0f / (1.0f + fastexp2(-bf2f(gv.z) * LOG2E));
    const float s3 = 1.0f / (1.0f + fastexp2(-bf2f(gv.w) * LOG2E));
    ushort4 ov;
    ov.x = f2bf(o0 * inv * s0);
    ov.y = f2bf(o1 * inv * s1);
    ov.z = f2bf(o2 * inv * s2);
    ov.w = f2bf(o3 * inv * s3);
    *(ushort4*)&aout[(size_t)row * 2048 + h * 64 + c4] = ov;
  }
}

extern "C" void kernel_launch(void* const* d_in, const int* in_sizes, int n_in,
                              void* d_out, int out_size, void* d_ws, size_t ws_size,
                              hipStream_t stream)
{
  const float* x  = (const float*)d_in[0];
  const float* cs = (const float*)d_in[1];
  const float* sn = (const float*)d_in[2];
  const float* wq = (const float*)d_in[3];
  const float* wk = (const float*)d_in[4];
  const float* wv = (const float*)d_in[5];
  const float* wo = (const float*)d_in[6];
  const float* wg = (const float*)d_in[7];
  const float* qn = (const float*)d_in[8];
  const float* kn = (const float*)d_in[9];
  float* out = (float*)d_out;

  u16* xb   = (u16*)d_ws;                      // 4M elems  (cast region, dead after qkvg gemm)
  u16* wqb  = xb  + (size_t)4194304;           // 4M
  u16* wkb  = wqb + (size_t)4194304;           // 1M
  u16* wvb  = wkb + (size_t)1048576;           // 1M
  u16* wgb  = wvb + (size_t)1048576;           // 4M
  u16* wob  = wgb + (size_t)4194304;           // 4M  (alive until final gemm)
  u16* qkvg = wob + (size_t)4194304;           // 2048*5120
  u16* vt   = qkvg + (size_t)2048 * 5120;      // 512*2048
  u16* aws  = vt   + (size_t)512 * 2048;       // 2048*2048

  u16*   part = xb;                                     // 32*80*4096 bf16 = 21 MB
  float* ml   = (float*)(xb + (size_t)32 * 80 * 4096);  // 32*80*64 fp32 = 0.64 MB

  k_cast<<<dim3(18432), 256, 0, stream>>>(x, xb, wq, wqb, wk, wkb, wv, wvb, wo, wob, wg, wgb);
  k_gemm_qkvg<<<dim3(16, 40), 256, 0, stream>>>(xb, wqb, wkb, wvb, wgb, cs, sn, qn, kn, qkvg);
  k_prep<<<dim3(256), 256, 0, stream>>>(qkvg, vt);
  k_attn_part<<<dim3(80, 16), 256, 0, stream>>>(qkvg, vt, part, ml);
  k_attn_comb<<<dim3(32, 32), 256, 0, stream>>>(part, ml, qkvg, aws);
  k_gemm_out<<<dim3(16, 32), 256, 0, stream>>>(aws, wob, out);
}

// Round 10
// 262.700 us; speedup vs baseline: 1.3284x; 1.3284x over previous
//
#include <hip/hip_runtime.h>
#include <stdint.h>

typedef unsigned short u16;
typedef unsigned int u32;
typedef __bf16 bf16x8 __attribute__((ext_vector_type(8)));
typedef __bf16 bf16x4 __attribute__((ext_vector_type(4)));
typedef float f32x4 __attribute__((ext_vector_type(4)));

__device__ __forceinline__ float bf2f(u16 u) {
  union { unsigned int i; float f; } v; v.i = ((unsigned int)u) << 16; return v.f;
}
__device__ __forceinline__ u16 f2bf(float f) {
  union { float f; unsigned int i; } v; v.f = f;
  unsigned int r = v.i + 0x7fffu + ((v.i >> 16) & 1u);
  return (u16)(r >> 16);
}
// raw v_exp_f32 (2^x): bounded args here, 1-ulp is plenty for bf16 P-values.
__device__ __forceinline__ float fastexp2(float x) {
  float r; asm("v_exp_f32 %0, %1" : "=v"(r) : "v"(x)); return r;
}
// async global->LDS, 16B per lane. LDS dest is wave-uniform base + lane*16.
__device__ __forceinline__ void ld16(const void* g, void* l) {
  __builtin_amdgcn_global_load_lds(
      (const __attribute__((address_space(1))) unsigned int*)g,
      (__attribute__((address_space(3))) unsigned int*)l, 16, 0, 0);
}

// fp32 -> bf16 cast of x + 5 weight matrices, one launch.
__global__ __launch_bounds__(256) void k_cast(
    const float* __restrict__ s0, u16* __restrict__ d0,
    const float* __restrict__ s1, u16* __restrict__ d1,
    const float* __restrict__ s2, u16* __restrict__ d2,
    const float* __restrict__ s3, u16* __restrict__ d3,
    const float* __restrict__ s4, u16* __restrict__ d4,
    const float* __restrict__ s5, u16* __restrict__ d5)
{
  int b = blockIdx.x;
  const float* s; u16* d;
  if (b < 4096)       { s = s0; d = d0; }
  else if (b < 8192)  { s = s1; d = d1; b -= 4096; }
  else if (b < 9216)  { s = s2; d = d2; b -= 8192; }
  else if (b < 10240) { s = s3; d = d3; b -= 9216; }
  else if (b < 14336) { s = s4; d = d4; b -= 10240; }
  else                { s = s5; d = d5; b -= 14336; }
  const int i = (b * 256 + threadIdx.x) * 4;
  const float4 v = *(const float4*)(s + i);
  ushort4 o;
  o.x = f2bf(v.x); o.y = f2bf(v.y); o.z = f2bf(v.z); o.w = f2bf(v.w);
  *(ushort4*)(d + i) = o;
}

// C[128 x 128] = A[128 x K] * B[128 x K]^T  (both K-contiguous bf16). BK=64,
// XOR-swizzled LDS (phys colgroup = cg ^ (row&7), applied on the GLOBAL source
// so global_load_lds destinations stay lane-contiguous).
template <typename OT>
__device__ __forceinline__ void gemm_body(
    const u16* __restrict__ A, int lda,
    const u16* __restrict__ B, int ldb,
    OT* __restrict__ C, int ldc, int K,
    u16* As, u16* Bs)
{
  const int tid = threadIdx.x;
  const int wave = tid >> 6, lane = tid & 63;
  const int wrow = (wave >> 1) * 64, wcol = (wave & 1) * 64;
  const int fr = lane & 15, kg = lane >> 4;
  const int srl = lane >> 3;
  const int scg = (lane & 7) ^ srl;

  f32x4 acc[4][4];
  const f32x4 z = {0.f, 0.f, 0.f, 0.f};
  for (int i = 0; i < 4; i++) for (int j = 0; j < 4; j++) acc[i][j] = z;

  const u16* Ag = A + (size_t)(wave * 8 + srl) * lda + scg * 8;
  const u16* Bg = B + (size_t)(wave * 8 + srl) * ldb + scg * 8;
  u16* Asw = As + wave * 8 * 64;
  u16* Bsw = Bs + wave * 8 * 64;
  const int sxr = fr & 7;

  for (int k0 = 0; k0 < K; k0 += 64) {
    for (int i = 0; i < 4; i++) {
      ld16(Ag + k0 + (size_t)(i * 32) * lda, Asw + i * 32 * 64);
      ld16(Bg + k0 + (size_t)(i * 32) * ldb, Bsw + i * 32 * 64);
    }
    __syncthreads();
    bf16x8 af[4][2], bfr[4][2];
    for (int i = 0; i < 4; i++)
      for (int h = 0; h < 2; h++) {
        af[i][h]  = *(const bf16x8*)&As[(wrow + i * 16 + fr) * 64 + (((h * 4 + kg) ^ sxr)) * 8];
        bfr[i][h] = *(const bf16x8*)&Bs[(wcol + i * 16 + fr) * 64 + (((h * 4 + kg) ^ sxr)) * 8];
      }
    for (int h = 0; h < 2; h++)
      for (int mi = 0; mi < 4; mi++)
        for (int ni = 0; ni < 4; ni++)
          acc[mi][ni] = __builtin_amdgcn_mfma_f32_16x16x32_bf16(af[mi][h], bfr[ni][h], acc[mi][ni], 0, 0, 0);
    __syncthreads();
  }
  const int er = kg * 4, ec = fr;
  for (int mi = 0; mi < 4; mi++)
    for (int ni = 0; ni < 4; ni++)
      for (int r = 0; r < 4; r++) {
        const float v = acc[mi][ni][r];
        OT* p = C + (size_t)(wrow + mi * 16 + er + r) * ldc + wcol + ni * 16 + ec;
        if constexpr (sizeof(OT) == 2) *p = (OT)f2bf(v); else *p = (OT)v;
      }
}

__global__ __launch_bounds__(256) void k_gemm_qkvg(
    const u16* __restrict__ x, const u16* __restrict__ wq, const u16* __restrict__ wk,
    const u16* __restrict__ wv, const u16* __restrict__ wg, u16* __restrict__ out)
{
  __shared__ __align__(16) u16 As[128 * 64];
  __shared__ __align__(16) u16 Bs[128 * 64];
  const int m0 = blockIdx.x * 128;
  const int c0 = blockIdx.y * 128;
  const u16* B; int br;
  if (c0 < 2048)      { B = wq; br = c0; }
  else if (c0 < 2560) { B = wk; br = c0 - 2048; }
  else if (c0 < 3072) { B = wv; br = c0 - 2560; }
  else                { B = wg; br = c0 - 3072; }
  gemm_body<u16>(x + (size_t)m0 * 2048, 2048, B + (size_t)br * 2048, 2048,
                 out + (size_t)m0 * 5120 + c0, 5120, 2048, As, Bs);
}

// 128(m) x 64(n) tile GEMM for the output projection: 512 blocks -> 2/CU.
__global__ __launch_bounds__(256) void k_gemm_out(
    const u16* __restrict__ a, const u16* __restrict__ wo, float* __restrict__ out)
{
  __shared__ __align__(16) u16 As[128 * 64];   // 16 KB
  __shared__ __align__(16) u16 Bs[64 * 64];    //  8 KB
  const int m0 = blockIdx.x * 128;
  const int c0 = blockIdx.y * 64;
  const int lda = 2048, ldb = 2048, ldc = 2048, K = 2048;
  const u16* A = a  + (size_t)m0 * lda;
  const u16* B = wo + (size_t)c0 * ldb;
  float* C = out + (size_t)m0 * ldc + c0;

  const int tid = threadIdx.x;
  const int wave = tid >> 6, lane = tid & 63;
  const int wrow = (wave >> 1) * 64, wcol = (wave & 1) * 32;
  const int fr = lane & 15, kg = lane >> 4;
  const int srl = lane >> 3;
  const int scg = (lane & 7) ^ srl;

  f32x4 acc[4][2];
  const f32x4 z = {0.f, 0.f, 0.f, 0.f};
  for (int i = 0; i < 4; i++) for (int j = 0; j < 2; j++) acc[i][j] = z;

  const u16* Ag = A + (size_t)(wave * 8 + srl) * lda + scg * 8;
  const u16* Bg = B + (size_t)(wave * 8 + srl) * ldb + scg * 8;
  u16* Asw = As + wave * 8 * 64;
  u16* Bsw = Bs + wave * 8 * 64;
  const int sxr = fr & 7;

  for (int k0 = 0; k0 < K; k0 += 64) {
#pragma unroll
    for (int i = 0; i < 4; i++)
      ld16(Ag + k0 + (size_t)(i * 32) * lda, Asw + i * 32 * 64);
#pragma unroll
    for (int i = 0; i < 2; i++)
      ld16(Bg + k0 + (size_t)(i * 32) * ldb, Bsw + i * 32 * 64);
    __syncthreads();
    bf16x8 af[4][2], bfr[2][2];
#pragma unroll
    for (int i = 0; i < 4; i++)
#pragma unroll
      for (int h = 0; h < 2; h++)
        af[i][h] = *(const bf16x8*)&As[(wrow + i * 16 + fr) * 64 + (((h * 4 + kg) ^ sxr)) * 8];
#pragma unroll
    for (int i = 0; i < 2; i++)
#pragma unroll
      for (int h = 0; h < 2; h++)
        bfr[i][h] = *(const bf16x8*)&Bs[(wcol + i * 16 + fr) * 64 + (((h * 4 + kg) ^ sxr)) * 8];
#pragma unroll
    for (int h = 0; h < 2; h++)
#pragma unroll
      for (int mi = 0; mi < 4; mi++)
#pragma unroll
        for (int ni = 0; ni < 2; ni++)
          acc[mi][ni] = __builtin_amdgcn_mfma_f32_16x16x32_bf16(af[mi][h], bfr[ni][h], acc[mi][ni], 0, 0, 0);
    __syncthreads();
  }
  const int er = kg * 4, ec = fr;
#pragma unroll
  for (int mi = 0; mi < 4; mi++)
#pragma unroll
    for (int ni = 0; ni < 2; ni++)
#pragma unroll
      for (int r = 0; r < 4; r++)
        C[(size_t)(wrow + mi * 16 + er + r) * ldc + wcol + ni * 16 + ec] = acc[mi][ni][r];
}

// Merged prep: RoPE+RMSNorm (blocks [0,10240)) and V-transpose (blocks [10240,10496)).
__global__ __launch_bounds__(256) void k_prep(
    u16* __restrict__ qkvg, const float* __restrict__ cosp, const float* __restrict__ sinp,
    const float* __restrict__ qn, const float* __restrict__ kn, u16* __restrict__ vt)
{
  __shared__ u16 Ls[64 * 72];
  if (blockIdx.x < 10240) {
    const int wid = (blockIdx.x * 256 + threadIdx.x) >> 6;
    const int lane = threadIdx.x & 63;
    const int s = wid / 20, hp = wid - s * 20;
    const int h = hp * 2 + (lane >> 5);
    const int j = lane & 31;
    u16* base; const float* wn;
    if (h < 32) { base = qkvg + (size_t)s * 5120 + h * 64;                wn = qn; }
    else        { base = qkvg + (size_t)s * 5120 + 2048 + (h - 32) * 64; wn = kn; }
    const unsigned int u = *(const unsigned int*)(base + 2 * j);
    const float xr = bf2f((u16)(u & 0xffffu)), xi = bf2f((u16)(u >> 16));
    const float c = cosp[s * 32 + j], sn = sinp[s * 32 + j];
    const float o0 = xr * c - xi * sn;
    const float o1 = xr * sn + xi * c;
    float ss = o0 * o0 + o1 * o1;
    for (int m = 1; m <= 16; m <<= 1) ss += __shfl_xor(ss, m, 64);
    const float inv = rsqrtf(ss * (1.0f / 64.0f) + 1e-6f);
    const u16 r0 = f2bf(o0 * inv * wn[2 * j]);
    const u16 r1 = f2bf(o1 * inv * wn[2 * j + 1]);
    *(unsigned int*)(base + 2 * j) = (unsigned int)r0 | ((unsigned int)r1 << 16);
  } else {
    const int bb = blockIdx.x - 10240;
    const int s0 = (bb & 31) * 64, g0 = (bb >> 5) * 64;
    const int tid = threadIdx.x;
    const int lr = tid >> 4, lc = (tid & 15) * 4;
    for (int p = 0; p < 4; p++) {
      const int r = p * 16 + lr;
      *(ushort4*)&Ls[r * 72 + lc] = *(const ushort4*)&qkvg[(size_t)(s0 + r) * 5120 + 2560 + g0 + lc];
    }
    __syncthreads();
    for (int p = 0; p < 4; p++) {
      const int r = p * 16 + lr;
      ushort4 o;
      o.x = Ls[(lc + 0) * 72 + r];
      o.y = Ls[(lc + 1) * 72 + r];
      o.z = Ls[(lc + 2) * 72 + r];
      o.w = Ls[(lc + 3) * 72 + r];
      *(ushort4*)&vt[(size_t)(g0 + r) * 2048 + s0 + lc] = o;
    }
  }
}

// ---- Split-KV flash attention pass 1, fixed-max softmax, SWAPPED QK^T,
// 2 q-heads per block (48 KB LDS, 3 blocks/CU, single-buffer K/V).
// R9: split-stage counted-vmcnt pipeline. Ks is only read by QK; Vs only by
// PV. So stageK(t+1) is issued right after the post-QK barrier (its latency
// hides under SM/PV) and stageV(t+1) after the post-PV barrier (hides under
// next iter's QK). Waits are vmcnt(4) -- the other stream's 4 loads stay in
// flight; never vmcnt(0) in the loop. LDS unchanged (48 KB, 3 blocks/CU).
__global__ __launch_bounds__(256, 3) void k_attn_part(
    const u16* __restrict__ qkvg, const u16* __restrict__ vt,
    u16* __restrict__ part, float* __restrict__ ml)
{
  __shared__ __align__(16) u16 SMEM[3 * 64 * 128];  // 48 KB
  u16* Ks = SMEM;               // [128 key][64 hd]  swizzled
  u16* Vs = SMEM + 8192;        // [64 hd][128 key]  swizzled
  u16* Ps = SMEM + 16384;       // [64 q][128 key]   swizzled
  const int c = blockIdx.x, gp = blockIdx.y;
  const int g = gp >> 1, h0 = (gp >> 1) * 4 + (gp & 1) * 2;   // heads h0, h0+1
  int qt, ci;
  if (c < 8)       { qt = c;                 ci = 0; }
  else if (c < 24) { qt = 8 + ((c - 8) >> 1);  ci = (c - 8) & 1; }
  else if (c < 48) { qt = 16 + (c - 24) / 3;   ci = (c - 24) % 3; }
  else             { qt = 24 + ((c - 48) >> 2); ci = (c - 48) & 3; }
  const int kb0 = ci * 512;
  const int kend = min(kb0 + 512, (qt + 1) * 64);
  const int q0 = qt * 64;
  const int tid = threadIdx.x, wave = tid >> 6, lane = tid & 63;
  const int fr = lane & 15, kg = lane >> 4;
  const int sx = fr & 7;

  // Stage the 64 x 128 Q slab (heads h0, h0+1 adjacent columns) through SMEM.
  {
    const u16* Qg = qkvg + (size_t)(q0 + wave * 16 + (lane >> 4)) * 5120 + h0 * 64 + (lane & 15) * 8;
#pragma unroll
    for (int i = 0; i < 4; i++)
      ld16(Qg + (size_t)(i * 4) * 5120, SMEM + (wave * 16 + i * 4) * 128);
  }
  __syncthreads();
  bf16x8 aq[2][2];
#pragma unroll
  for (int hh = 0; hh < 2; hh++)
#pragma unroll
    for (int hf = 0; hf < 2; hf++)
      aq[hh][hf] = *(const bf16x8*)&SMEM[(wave * 16 + fr) * 128 + hh * 64 + hf * 32 + kg * 8];
  __syncthreads();   // Q reads done; Ks/Vs regions are free for staging

  f32x4 o[2][4];
  const f32x4 z = {0.f, 0.f, 0.f, 0.f};
#pragma unroll
  for (int hh = 0; hh < 2; hh++)
#pragma unroll
    for (int i = 0; i < 4; i++) o[hh][i] = z;
  float L[2] = {0.f, 0.f};
  const int qrow = q0 + wave * 16 + fr;      // this lane's q-row (swapped layout)
  const int prow = wave * 16 + fr;           // P-tile row owned by this lane

  const int krl = wave * 8 + (lane >> 3);
  const int kcg = (lane & 7) ^ (krl & 7);
  const int vrl = wave * 4 + kg;
  const int vcg = fr ^ (vrl & 7);

  // 4 ld16/wave per stage stream.
  auto stageK = [&](int kb_) {
    const u16* Kg = qkvg + (size_t)(kb_ + krl) * 5120 + 2048 + g * 64 + kcg * 8;
#pragma unroll
    for (int i = 0; i < 4; i++)
      ld16(Kg + (size_t)(i * 32) * 5120, Ks + (i * 32 + wave * 8) * 64);
  };
  auto stageV = [&](int kb_) {
    const u16* Vg = vt + (size_t)(g * 64 + vrl) * 2048 + kb_ + vcg * 8;
#pragma unroll
    for (int i = 0; i < 4; i++)
      ld16(Vg + (size_t)(i * 16) * 2048, Vs + (i * 16 + wave * 4) * 128);
  };

  stageK(kb0);                               // prologue: K(0) then V(0)
  stageV(kb0);                               // loop invariant: 8 loads in flight

  for (int kb = kb0; kb < kend; kb += 128) {
    const int kbn = (kb + 128 < kend) ? kb + 128 : kb;   // clamped dummy tail

    asm volatile("s_waitcnt vmcnt(4)" ::: "memory");     // my K(t) landed
    __builtin_amdgcn_s_barrier();                        // everyone's K(t) landed

    // ---- QK for BOTH heads, sharing the K-fragment loads.
    f32x4 s0[8], s1[8];
#pragma unroll
    for (int i = 0; i < 8; i++) { s0[i] = z; s1[i] = z; }
    __builtin_amdgcn_s_setprio(1);
#pragma unroll
    for (int ni = 0; ni < 8; ni++) {
      const bf16x8 bk0 = *(const bf16x8*)&Ks[(ni * 16 + fr) * 64 + ((kg ^ sx)) * 8];
      const bf16x8 bk1 = *(const bf16x8*)&Ks[(ni * 16 + fr) * 64 + (((kg + 4) ^ sx)) * 8];
      s0[ni] = __builtin_amdgcn_mfma_f32_16x16x32_bf16(bk0, aq[0][0], s0[ni], 0, 0, 0);
      s0[ni] = __builtin_amdgcn_mfma_f32_16x16x32_bf16(bk1, aq[0][1], s0[ni], 0, 0, 0);
      s1[ni] = __builtin_amdgcn_mfma_f32_16x16x32_bf16(bk0, aq[1][0], s1[ni], 0, 0, 0);
      s1[ni] = __builtin_amdgcn_mfma_f32_16x16x32_bf16(bk1, aq[1][1], s1[ni], 0, 0, 0);
    }
    __builtin_amdgcn_s_setprio(0);
    __builtin_amdgcn_s_barrier();                        // Ks reads done block-wide
    stageK(kbn);                                         // K(t+1) -> Ks (hides under SM/PV)
    asm volatile("s_waitcnt vmcnt(4)" ::: "memory");     // my V(t) landed
    __builtin_amdgcn_s_barrier();                        // everyone's V(t) landed

    const bool masked = (kb + 127 > q0 + wave * 16);     // wave-uniform
    u32* Ps32 = (u32*)Ps;
    const int pb32 = prow * 64;

    // ---- head 0 softmax -> P-tile (one b64 store per ni)
    {
      float Lh = 0.f;
      if (masked) {
#pragma unroll
        for (int ni = 0; ni < 8; ni++) {
          const int dlim = qrow - (kb + ni * 16 + kg * 4);
          float p0 = fastexp2(fmaf(s0[ni][0], 0.18033688f, -11.5415603f));
          float p1 = fastexp2(fmaf(s0[ni][1], 0.18033688f, -11.5415603f));
          float p2 = fastexp2(fmaf(s0[ni][2], 0.18033688f, -11.5415603f));
          float p3 = fastexp2(fmaf(s0[ni][3], 0.18033688f, -11.5415603f));
          p0 = (0 <= dlim) ? p0 : 0.f;
          p1 = (1 <= dlim) ? p1 : 0.f;
          p2 = (2 <= dlim) ? p2 : 0.f;
          p3 = (3 <= dlim) ? p3 : 0.f;
          Lh += (p0 + p1) + (p2 + p3);
          bf16x4 w;
          w[0] = (__bf16)p0; w[1] = (__bf16)p1; w[2] = (__bf16)p2; w[3] = (__bf16)p3;
          *(bf16x4*)&Ps32[pb32 + ((2 * ni + (kg >> 1)) ^ sx) * 4 + (kg & 1) * 2] = w;
        }
      } else {
#pragma unroll
        for (int ni = 0; ni < 8; ni++) {
          float p0 = fastexp2(fmaf(s0[ni][0], 0.18033688f, -11.5415603f));
          float p1 = fastexp2(fmaf(s0[ni][1], 0.18033688f, -11.5415603f));
          float p2 = fastexp2(fmaf(s0[ni][2], 0.18033688f, -11.5415603f));
          float p3 = fastexp2(fmaf(s0[ni][3], 0.18033688f, -11.5415603f));
          Lh += (p0 + p1) + (p2 + p3);
          bf16x4 w;
          w[0] = (__bf16)p0; w[1] = (__bf16)p1; w[2] = (__bf16)p2; w[3] = (__bf16)p3;
          *(bf16x4*)&Ps32[pb32 + ((2 * ni + (kg >> 1)) ^ sx) * 4 + (kg & 1) * 2] = w;
        }
      }
      L[0] += Lh;
    }
    // ---- head 0 PV (in-wave produce/consume of wave-private P rows)
    __builtin_amdgcn_s_setprio(1);
#pragma unroll
    for (int k0 = 0; k0 < 128; k0 += 32) {
      const bf16x8 ap = *(const bf16x8*)&Ps[prow * 128 + ((((k0 >> 3) + kg)) ^ sx) * 8];
#pragma unroll
      for (int ni = 0; ni < 4; ni++) {
        const bf16x8 bv = *(const bf16x8*)&Vs[(ni * 16 + fr) * 128 + (((k0 >> 3) + kg) ^ sx) * 8];
        o[0][ni] = __builtin_amdgcn_mfma_f32_16x16x32_bf16(ap, bv, o[0][ni], 0, 0, 0);
      }
    }
    __builtin_amdgcn_s_setprio(0);

    // ---- head 1 softmax (VALU; overlaps PV0's MFMA) -> P-tile overwrite
    {
      float Lh = 0.f;
      if (masked) {
#pragma unroll
        for (int ni = 0; ni < 8; ni++) {
          const int dlim = qrow - (kb + ni * 16 + kg * 4);
          float p0 = fastexp2(fmaf(s1[ni][0], 0.18033688f, -11.5415603f));
          float p1 = fastexp2(fmaf(s1[ni][1], 0.18033688f, -11.5415603f));
          float p2 = fastexp2(fmaf(s1[ni][2], 0.18033688f, -11.5415603f));
          float p3 = fastexp2(fmaf(s1[ni][3], 0.18033688f, -11.5415603f));
          p0 = (0 <= dlim) ? p0 : 0.f;
          p1 = (1 <= dlim) ? p1 : 0.f;
          p2 = (2 <= dlim) ? p2 : 0.f;
          p3 = (3 <= dlim) ? p3 : 0.f;
          Lh += (p0 + p1) + (p2 + p3);
          bf16x4 w;
          w[0] = (__bf16)p0; w[1] = (__bf16)p1; w[2] = (__bf16)p2; w[3] = (__bf16)p3;
          *(bf16x4*)&Ps32[pb32 + ((2 * ni + (kg >> 1)) ^ sx) * 4 + (kg & 1) * 2] = w;
        }
      } else {
#pragma unroll
        for (int ni = 0; ni < 8; ni++) {
          float p0 = fastexp2(fmaf(s1[ni][0], 0.18033688f, -11.5415603f));
          float p1 = fastexp2(fmaf(s1[ni][1], 0.18033688f, -11.5415603f));
          float p2 = fastexp2(fmaf(s1[ni][2], 0.18033688f, -11.5415603f));
          float p3 = fastexp2(fmaf(s1[ni][3], 0.18033688f, -11.5415603f));
          Lh += (p0 + p1) + (p2 + p3);
          bf16x4 w;
          w[0] = (__bf16)p0; w[1] = (__bf16)p1; w[2] = (__bf16)p2; w[3] = (__bf16)p3;
          *(bf16x4*)&Ps32[pb32 + ((2 * ni + (kg >> 1)) ^ sx) * 4 + (kg & 1) * 2] = w;
        }
      }
      L[1] += Lh;
    }
    // ---- head 1 PV
    __builtin_amdgcn_s_setprio(1);
#pragma unroll
    for (int k0 = 0; k0 < 128; k0 += 32) {
      const bf16x8 ap = *(const bf16x8*)&Ps[prow * 128 + ((((k0 >> 3) + kg)) ^ sx) * 8];
#pragma unroll
      for (int ni = 0; ni < 4; ni++) {
        const bf16x8 bv = *(const bf16x8*)&Vs[(ni * 16 + fr) * 128 + (((k0 >> 3) + kg) ^ sx) * 8];
        o[1][ni] = __builtin_amdgcn_mfma_f32_16x16x32_bf16(ap, bv, o[1][ni], 0, 0, 0);
      }
    }
    __builtin_amdgcn_s_setprio(0);
    __builtin_amdgcn_s_barrier();                        // Vs/Ps reads done block-wide
    stageV(kbn);                                         // V(t+1) -> Vs (hides under next QK)
  }
  // Drain in-flight LDS writes before the block can exit (LDS is reallocated).
  asm volatile("s_waitcnt vmcnt(0)" ::: "memory");

#pragma unroll
  for (int hh = 0; hh < 2; hh++) {
    float Lh = L[hh];
    Lh += __shfl_xor(Lh, 16, 64);
    Lh += __shfl_xor(Lh, 32, 64);
    const int h = h0 + hh;
    const int pbase = (h * 80 + c) * 4096;
#pragma unroll
    for (int ni = 0; ni < 4; ni++)
#pragma unroll
      for (int r = 0; r < 4; r++)
        part[pbase + (wave * 16 + kg * 4 + r) * 64 + ni * 16 + fr] = f2bf(o[hh][ni][r]);
    if (lane < 16) ml[(h * 80 + c) * 64 + wave * 16 + fr] = Lh;
  }
}

// ---- Split-KV pass 2: plain sums (shared fixed max); fuse sigmoid gating.
// Vectorized: each thread owns 4 cols (ushort4) x 4 rows -> 8 B/lane memory ops.
__global__ __launch_bounds__(256) void k_attn_comb(
    const u16* __restrict__ part, const float* __restrict__ ml,
    const u16* __restrict__ qkvg, u16* __restrict__ aout)
{
  const int qt = blockIdx.x, h = blockIdx.y;
  int cb, nch;
  if (qt < 8)       { cb = qt;               nch = 1; }
  else if (qt < 16) { cb = 8 + 2 * (qt - 8);  nch = 2; }
  else if (qt < 24) { cb = 24 + 3 * (qt - 16); nch = 3; }
  else              { cb = 48 + 4 * (qt - 24); nch = 4; }
  const int c4 = (threadIdx.x & 15) * 4;     // column base within the head
  const int rg = threadIdx.x >> 4;           // 0..15
  const float LOG2E = 1.44269504f;
#pragma unroll
  for (int rr = 0; rr < 4; rr++) {
    const int rl = rr * 16 + rg;
    const int row = qt * 64 + rl;
    float L = 0.f, o0 = 0.f, o1 = 0.f, o2 = 0.f, o3 = 0.f;
    for (int cc = 0; cc < nch; cc++) {
      L += ml[(h * 80 + cb + cc) * 64 + rl];
      const ushort4 pv = *(const ushort4*)&part[(size_t)(h * 80 + cb + cc) * 4096 + rl * 64 + c4];
      o0 += bf2f(pv.x); o1 += bf2f(pv.y); o2 += bf2f(pv.z); o3 += bf2f(pv.w);
    }
    const ushort4 gv = *(const ushort4*)&qkvg[(size_t)row * 5120 + 3072 + h * 64 + c4];
    const float inv = 1.0f / L;
    const float s0 = 1.0f / (1.0f + fastexp2(-bf2f(gv.x) * LOG2E));
    const float s1 = 1.0f / (1.0f + fastexp2(-bf2f(gv.y) * LOG2E));
    const float s2 = 1.0f / (1.0f + fastexp2(-bf2f(gv.z) * LOG2E));
    const float s3 = 1.0f / (1.0f + fastexp2(-bf2f(gv.w) * LOG2E));
    ushort4 ov;
    ov.x = f2bf(o0 * inv * s0);
    ov.y = f2bf(o1 * inv * s1);
    ov.z = f2bf(o2 * inv * s2);
    ov.w = f2bf(o3 * inv * s3);
    *(ushort4*)&aout[(size_t)row * 2048 + h * 64 + c4] = ov;
  }
}

extern "C" void kernel_launch(void* const* d_in, const int* in_sizes, int n_in,
                              void* d_out, int out_size, void* d_ws, size_t ws_size,
                              hipStream_t stream)
{
  const float* x  = (const float*)d_in[0];
  const float* cs = (const float*)d_in[1];
  const float* sn = (const float*)d_in[2];
  const float* wq = (const float*)d_in[3];
  const float* wk = (const float*)d_in[4];
  const float* wv = (const float*)d_in[5];
  const float* wo = (const float*)d_in[6];
  const float* wg = (const float*)d_in[7];
  const float* qn = (const float*)d_in[8];
  const float* kn = (const float*)d_in[9];
  float* out = (float*)d_out;

  u16* xb   = (u16*)d_ws;                      // 4M elems  (cast region, dead after qkvg gemm)
  u16* wqb  = xb  + (size_t)4194304;           // 4M
  u16* wkb  = wqb + (size_t)4194304;           // 1M
  u16* wvb  = wkb + (size_t)1048576;           // 1M
  u16* wgb  = wvb + (size_t)1048576;           // 4M
  u16* wob  = wgb + (size_t)4194304;           // 4M  (alive until final gemm)
  u16* qkvg = wob + (size_t)4194304;           // 2048*5120
  u16* vt   = qkvg + (size_t)2048 * 5120;      // 512*2048
  u16* aws  = vt   + (size_t)512 * 2048;       // 2048*2048

  u16*   part = xb;                                     // 32*80*4096 bf16 = 21 MB
  float* ml   = (float*)(xb + (size_t)32 * 80 * 4096);  // 32*80*64 fp32 = 0.64 MB

  k_cast<<<dim3(18432), 256, 0, stream>>>(x, xb, wq, wqb, wk, wkb, wv, wvb, wo, wob, wg, wgb);
  k_gemm_qkvg<<<dim3(16, 40), 256, 0, stream>>>(xb, wqb, wkb, wvb, wgb, qkvg);
  k_prep<<<dim3(10240 + 256), 256, 0, stream>>>(qkvg, cs, sn, qn, kn, vt);
  k_attn_part<<<dim3(80, 16), 256, 0, stream>>>(qkvg, vt, part, ml);
  k_attn_comb<<<dim3(32, 32), 256, 0, stream>>>(part, ml, qkvg, aws);
  k_gemm_out<<<dim3(16, 32), 256, 0, stream>>>(aws, wob, out);
}

// Round 11
// 258.066 us; speedup vs baseline: 1.3523x; 1.0180x over previous
//
#include <hip/hip_runtime.h>
#include <stdint.h>

typedef unsigned short u16;
typedef unsigned int u32;
typedef __bf16 bf16x8 __attribute__((ext_vector_type(8)));
typedef __bf16 bf16x4 __attribute__((ext_vector_type(4)));
typedef float f32x4 __attribute__((ext_vector_type(4)));

__device__ __forceinline__ float bf2f(u16 u) {
  union { unsigned int i; float f; } v; v.i = ((unsigned int)u) << 16; return v.f;
}
__device__ __forceinline__ u16 f2bf(float f) {
  union { float f; unsigned int i; } v; v.f = f;
  unsigned int r = v.i + 0x7fffu + ((v.i >> 16) & 1u);
  return (u16)(r >> 16);
}
// raw v_exp_f32 (2^x): bounded args here, 1-ulp is plenty for bf16 P-values.
__device__ __forceinline__ float fastexp2(float x) {
  float r; asm("v_exp_f32 %0, %1" : "=v"(r) : "v"(x)); return r;
}
// async global->LDS, 16B per lane. LDS dest is wave-uniform base + lane*16.
__device__ __forceinline__ void ld16(const void* g, void* l) {
  __builtin_amdgcn_global_load_lds(
      (const __attribute__((address_space(1))) unsigned int*)g,
      (__attribute__((address_space(3))) unsigned int*)l, 16, 0, 0);
}

// fp32 -> bf16 cast of x + 5 weight matrices, one launch.
__global__ __launch_bounds__(256) void k_cast(
    const float* __restrict__ s0, u16* __restrict__ d0,
    const float* __restrict__ s1, u16* __restrict__ d1,
    const float* __restrict__ s2, u16* __restrict__ d2,
    const float* __restrict__ s3, u16* __restrict__ d3,
    const float* __restrict__ s4, u16* __restrict__ d4,
    const float* __restrict__ s5, u16* __restrict__ d5)
{
  int b = blockIdx.x;
  const float* s; u16* d;
  if (b < 4096)       { s = s0; d = d0; }
  else if (b < 8192)  { s = s1; d = d1; b -= 4096; }
  else if (b < 9216)  { s = s2; d = d2; b -= 8192; }
  else if (b < 10240) { s = s3; d = d3; b -= 9216; }
  else if (b < 14336) { s = s4; d = d4; b -= 10240; }
  else                { s = s5; d = d5; b -= 14336; }
  const int i = (b * 256 + threadIdx.x) * 4;
  const float4 v = *(const float4*)(s + i);
  ushort4 o;
  o.x = f2bf(v.x); o.y = f2bf(v.y); o.z = f2bf(v.z); o.w = f2bf(v.w);
  *(ushort4*)(d + i) = o;
}

// C[128 x 128] = A[128 x K] * B[128 x K]^T  (both K-contiguous bf16). BK=64,
// XOR-swizzled LDS (phys colgroup = cg ^ (row&7), applied on the GLOBAL source
// so global_load_lds destinations stay lane-contiguous).
template <typename OT>
__device__ __forceinline__ void gemm_body(
    const u16* __restrict__ A, int lda,
    const u16* __restrict__ B, int ldb,
    OT* __restrict__ C, int ldc, int K,
    u16* As, u16* Bs)
{
  const int tid = threadIdx.x;
  const int wave = tid >> 6, lane = tid & 63;
  const int wrow = (wave >> 1) * 64, wcol = (wave & 1) * 64;
  const int fr = lane & 15, kg = lane >> 4;
  const int srl = lane >> 3;
  const int scg = (lane & 7) ^ srl;

  f32x4 acc[4][4];
  const f32x4 z = {0.f, 0.f, 0.f, 0.f};
  for (int i = 0; i < 4; i++) for (int j = 0; j < 4; j++) acc[i][j] = z;

  const u16* Ag = A + (size_t)(wave * 8 + srl) * lda + scg * 8;
  const u16* Bg = B + (size_t)(wave * 8 + srl) * ldb + scg * 8;
  u16* Asw = As + wave * 8 * 64;
  u16* Bsw = Bs + wave * 8 * 64;
  const int sxr = fr & 7;

  for (int k0 = 0; k0 < K; k0 += 64) {
    for (int i = 0; i < 4; i++) {
      ld16(Ag + k0 + (size_t)(i * 32) * lda, Asw + i * 32 * 64);
      ld16(Bg + k0 + (size_t)(i * 32) * ldb, Bsw + i * 32 * 64);
    }
    __syncthreads();
    bf16x8 af[4][2], bfr[4][2];
    for (int i = 0; i < 4; i++)
      for (int h = 0; h < 2; h++) {
        af[i][h]  = *(const bf16x8*)&As[(wrow + i * 16 + fr) * 64 + (((h * 4 + kg) ^ sxr)) * 8];
        bfr[i][h] = *(const bf16x8*)&Bs[(wcol + i * 16 + fr) * 64 + (((h * 4 + kg) ^ sxr)) * 8];
      }
    for (int h = 0; h < 2; h++)
      for (int mi = 0; mi < 4; mi++)
        for (int ni = 0; ni < 4; ni++)
          acc[mi][ni] = __builtin_amdgcn_mfma_f32_16x16x32_bf16(af[mi][h], bfr[ni][h], acc[mi][ni], 0, 0, 0);
    __syncthreads();
  }
  const int er = kg * 4, ec = fr;
  for (int mi = 0; mi < 4; mi++)
    for (int ni = 0; ni < 4; ni++)
      for (int r = 0; r < 4; r++) {
        const float v = acc[mi][ni][r];
        OT* p = C + (size_t)(wrow + mi * 16 + er + r) * ldc + wcol + ni * 16 + ec;
        if constexpr (sizeof(OT) == 2) *p = (OT)f2bf(v); else *p = (OT)v;
      }
}

__global__ __launch_bounds__(256) void k_gemm_qkvg(
    const u16* __restrict__ x, const u16* __restrict__ wq, const u16* __restrict__ wk,
    const u16* __restrict__ wv, const u16* __restrict__ wg, u16* __restrict__ out)
{
  __shared__ __align__(16) u16 As[128 * 64];
  __shared__ __align__(16) u16 Bs[128 * 64];
  const int m0 = blockIdx.x * 128;
  const int c0 = blockIdx.y * 128;
  const u16* B; int br;
  if (c0 < 2048)      { B = wq; br = c0; }
  else if (c0 < 2560) { B = wk; br = c0 - 2048; }
  else if (c0 < 3072) { B = wv; br = c0 - 2560; }
  else                { B = wg; br = c0 - 3072; }
  gemm_body<u16>(x + (size_t)m0 * 2048, 2048, B + (size_t)br * 2048, 2048,
                 out + (size_t)m0 * 5120 + c0, 5120, 2048, As, Bs);
}

// 128(m) x 64(n) tile GEMM for the output projection: 512 blocks -> 2/CU.
__global__ __launch_bounds__(256) void k_gemm_out(
    const u16* __restrict__ a, const u16* __restrict__ wo, float* __restrict__ out)
{
  __shared__ __align__(16) u16 As[128 * 64];   // 16 KB
  __shared__ __align__(16) u16 Bs[64 * 64];    //  8 KB
  const int m0 = blockIdx.x * 128;
  const int c0 = blockIdx.y * 64;
  const int lda = 2048, ldb = 2048, ldc = 2048, K = 2048;
  const u16* A = a  + (size_t)m0 * lda;
  const u16* B = wo + (size_t)c0 * ldb;
  float* C = out + (size_t)m0 * ldc + c0;

  const int tid = threadIdx.x;
  const int wave = tid >> 6, lane = tid & 63;
  const int wrow = (wave >> 1) * 64, wcol = (wave & 1) * 32;
  const int fr = lane & 15, kg = lane >> 4;
  const int srl = lane >> 3;
  const int scg = (lane & 7) ^ srl;

  f32x4 acc[4][2];
  const f32x4 z = {0.f, 0.f, 0.f, 0.f};
  for (int i = 0; i < 4; i++) for (int j = 0; j < 2; j++) acc[i][j] = z;

  const u16* Ag = A + (size_t)(wave * 8 + srl) * lda + scg * 8;
  const u16* Bg = B + (size_t)(wave * 8 + srl) * ldb + scg * 8;
  u16* Asw = As + wave * 8 * 64;
  u16* Bsw = Bs + wave * 8 * 64;
  const int sxr = fr & 7;

  for (int k0 = 0; k0 < K; k0 += 64) {
#pragma unroll
    for (int i = 0; i < 4; i++)
      ld16(Ag + k0 + (size_t)(i * 32) * lda, Asw + i * 32 * 64);
#pragma unroll
    for (int i = 0; i < 2; i++)
      ld16(Bg + k0 + (size_t)(i * 32) * ldb, Bsw + i * 32 * 64);
    __syncthreads();
    bf16x8 af[4][2], bfr[2][2];
#pragma unroll
    for (int i = 0; i < 4; i++)
#pragma unroll
      for (int h = 0; h < 2; h++)
        af[i][h] = *(const bf16x8*)&As[(wrow + i * 16 + fr) * 64 + (((h * 4 + kg) ^ sxr)) * 8];
#pragma unroll
    for (int i = 0; i < 2; i++)
#pragma unroll
      for (int h = 0; h < 2; h++)
        bfr[i][h] = *(const bf16x8*)&Bs[(wcol + i * 16 + fr) * 64 + (((h * 4 + kg) ^ sxr)) * 8];
#pragma unroll
    for (int h = 0; h < 2; h++)
#pragma unroll
      for (int mi = 0; mi < 4; mi++)
#pragma unroll
        for (int ni = 0; ni < 2; ni++)
          acc[mi][ni] = __builtin_amdgcn_mfma_f32_16x16x32_bf16(af[mi][h], bfr[ni][h], acc[mi][ni], 0, 0, 0);
    __syncthreads();
  }
  const int er = kg * 4, ec = fr;
#pragma unroll
  for (int mi = 0; mi < 4; mi++)
#pragma unroll
    for (int ni = 0; ni < 2; ni++)
#pragma unroll
      for (int r = 0; r < 4; r++)
        C[(size_t)(wrow + mi * 16 + er + r) * ldc + wcol + ni * 16 + ec] = acc[mi][ni][r];
}

// Merged prep: RoPE+RMSNorm (blocks [0,10240)) and V-transpose (blocks [10240,10496)).
__global__ __launch_bounds__(256) void k_prep(
    u16* __restrict__ qkvg, const float* __restrict__ cosp, const float* __restrict__ sinp,
    const float* __restrict__ qn, const float* __restrict__ kn, u16* __restrict__ vt)
{
  __shared__ u16 Ls[64 * 72];
  if (blockIdx.x < 10240) {
    const int wid = (blockIdx.x * 256 + threadIdx.x) >> 6;
    const int lane = threadIdx.x & 63;
    const int s = wid / 20, hp = wid - s * 20;
    const int h = hp * 2 + (lane >> 5);
    const int j = lane & 31;
    u16* base; const float* wn;
    if (h < 32) { base = qkvg + (size_t)s * 5120 + h * 64;                wn = qn; }
    else        { base = qkvg + (size_t)s * 5120 + 2048 + (h - 32) * 64; wn = kn; }
    const unsigned int u = *(const unsigned int*)(base + 2 * j);
    const float xr = bf2f((u16)(u & 0xffffu)), xi = bf2f((u16)(u >> 16));
    const float c = cosp[s * 32 + j], sn = sinp[s * 32 + j];
    const float o0 = xr * c - xi * sn;
    const float o1 = xr * sn + xi * c;
    float ss = o0 * o0 + o1 * o1;
    for (int m = 1; m <= 16; m <<= 1) ss += __shfl_xor(ss, m, 64);
    const float inv = rsqrtf(ss * (1.0f / 64.0f) + 1e-6f);
    const u16 r0 = f2bf(o0 * inv * wn[2 * j]);
    const u16 r1 = f2bf(o1 * inv * wn[2 * j + 1]);
    *(unsigned int*)(base + 2 * j) = (unsigned int)r0 | ((unsigned int)r1 << 16);
  } else {
    const int bb = blockIdx.x - 10240;
    const int s0 = (bb & 31) * 64, g0 = (bb >> 5) * 64;
    const int tid = threadIdx.x;
    const int lr = tid >> 4, lc = (tid & 15) * 4;
    for (int p = 0; p < 4; p++) {
      const int r = p * 16 + lr;
      *(ushort4*)&Ls[r * 72 + lc] = *(const ushort4*)&qkvg[(size_t)(s0 + r) * 5120 + 2560 + g0 + lc];
    }
    __syncthreads();
    for (int p = 0; p < 4; p++) {
      const int r = p * 16 + lr;
      ushort4 o;
      o.x = Ls[(lc + 0) * 72 + r];
      o.y = Ls[(lc + 1) * 72 + r];
      o.z = Ls[(lc + 2) * 72 + r];
      o.w = Ls[(lc + 3) * 72 + r];
      *(ushort4*)&vt[(size_t)(g0 + r) * 2048 + s0 + lc] = o;
    }
  }
}

// ---- Split-KV flash attention pass 1, fixed-max softmax, SWAPPED QK^T,
// 2 q-heads per block. R10: HALVED P-tile (64x64, 8 KB) -> LDS 40 KB ->
// 4 blocks/CU (16 waves, +33% TLP). Per head: SM+PV run in two 64-key
// halves through the same Ps buffer (wave-private rows, in-order per-wave
// DS -> no barrier between halves). Mask check refined per half: in
// diagonal tiles half 0 is provably unmasked. Keeps R9's split-stage
// counted-vmcnt K/V pipeline (vmcnt(4), never 0 in-loop).
__global__ __launch_bounds__(256, 3) void k_attn_part(
    const u16* __restrict__ qkvg, const u16* __restrict__ vt,
    u16* __restrict__ part, float* __restrict__ ml)
{
  __shared__ __align__(16) u16 SMEM[8192 + 8192 + 4096];  // 40 KB
  u16* Ks = SMEM;               // [128 key][64 hd]  swizzled (16 KB)
  u16* Vs = SMEM + 8192;        // [64 hd][128 key]  swizzled (16 KB)
  u16* Ps = SMEM + 16384;       // [64 q][64 key]    swizzled ( 8 KB)
  const int c = blockIdx.x, gp = blockIdx.y;
  const int g = gp >> 1, h0 = (gp >> 1) * 4 + (gp & 1) * 2;   // heads h0, h0+1
  int qt, ci;
  if (c < 8)       { qt = c;                 ci = 0; }
  else if (c < 24) { qt = 8 + ((c - 8) >> 1);  ci = (c - 8) & 1; }
  else if (c < 48) { qt = 16 + (c - 24) / 3;   ci = (c - 24) % 3; }
  else             { qt = 24 + ((c - 48) >> 2); ci = (c - 48) & 3; }
  const int kb0 = ci * 512;
  const int kend = min(kb0 + 512, (qt + 1) * 64);
  const int q0 = qt * 64;
  const int tid = threadIdx.x, wave = tid >> 6, lane = tid & 63;
  const int fr = lane & 15, kg = lane >> 4;
  const int sx = fr & 7;

  // Stage the 64 x 128 Q slab (heads h0, h0+1 adjacent columns) through SMEM.
  {
    const u16* Qg = qkvg + (size_t)(q0 + wave * 16 + (lane >> 4)) * 5120 + h0 * 64 + (lane & 15) * 8;
#pragma unroll
    for (int i = 0; i < 4; i++)
      ld16(Qg + (size_t)(i * 4) * 5120, SMEM + (wave * 16 + i * 4) * 128);
  }
  __syncthreads();
  bf16x8 aq[2][2];
#pragma unroll
  for (int hh = 0; hh < 2; hh++)
#pragma unroll
    for (int hf = 0; hf < 2; hf++)
      aq[hh][hf] = *(const bf16x8*)&SMEM[(wave * 16 + fr) * 128 + hh * 64 + hf * 32 + kg * 8];
  __syncthreads();   // Q reads done; Ks/Vs regions are free for staging

  f32x4 o[2][4];
  const f32x4 z = {0.f, 0.f, 0.f, 0.f};
#pragma unroll
  for (int hh = 0; hh < 2; hh++)
#pragma unroll
    for (int i = 0; i < 4; i++) o[hh][i] = z;
  float L[2] = {0.f, 0.f};
  const int qrow = q0 + wave * 16 + fr;      // this lane's q-row (swapped layout)
  const int qrowW = q0 + wave * 16;          // wave's min q-row
  const int prow = wave * 16 + fr;           // P-tile row owned by this lane

  const int krl = wave * 8 + (lane >> 3);
  const int kcg = (lane & 7) ^ (krl & 7);
  const int vrl = wave * 4 + kg;
  const int vcg = fr ^ (vrl & 7);

  // 4 ld16/wave per stage stream.
  auto stageK = [&](int kb_) {
    const u16* Kg = qkvg + (size_t)(kb_ + krl) * 5120 + 2048 + g * 64 + kcg * 8;
#pragma unroll
    for (int i = 0; i < 4; i++)
      ld16(Kg + (size_t)(i * 32) * 5120, Ks + (i * 32 + wave * 8) * 64);
  };
  auto stageV = [&](int kb_) {
    const u16* Vg = vt + (size_t)(g * 64 + vrl) * 2048 + kb_ + vcg * 8;
#pragma unroll
    for (int i = 0; i < 4; i++)
      ld16(Vg + (size_t)(i * 16) * 2048, Vs + (i * 16 + wave * 4) * 128);
  };

  stageK(kb0);                               // prologue: K(0) then V(0)
  stageV(kb0);                               // loop invariant: 8 loads in flight

  for (int kb = kb0; kb < kend; kb += 128) {
    const int kbn = (kb + 128 < kend) ? kb + 128 : kb;   // clamped dummy tail

    asm volatile("s_waitcnt vmcnt(4)" ::: "memory");     // my K(t) landed
    __builtin_amdgcn_s_barrier();                        // everyone's K(t) landed

    // ---- QK for BOTH heads, sharing the K-fragment loads.
    f32x4 s0[8], s1[8];
#pragma unroll
    for (int i = 0; i < 8; i++) { s0[i] = z; s1[i] = z; }
    __builtin_amdgcn_s_setprio(1);
#pragma unroll
    for (int ni = 0; ni < 8; ni++) {
      const bf16x8 bk0 = *(const bf16x8*)&Ks[(ni * 16 + fr) * 64 + ((kg ^ sx)) * 8];
      const bf16x8 bk1 = *(const bf16x8*)&Ks[(ni * 16 + fr) * 64 + (((kg + 4) ^ sx)) * 8];
      s0[ni] = __builtin_amdgcn_mfma_f32_16x16x32_bf16(bk0, aq[0][0], s0[ni], 0, 0, 0);
      s0[ni] = __builtin_amdgcn_mfma_f32_16x16x32_bf16(bk1, aq[0][1], s0[ni], 0, 0, 0);
      s1[ni] = __builtin_amdgcn_mfma_f32_16x16x32_bf16(bk0, aq[1][0], s1[ni], 0, 0, 0);
      s1[ni] = __builtin_amdgcn_mfma_f32_16x16x32_bf16(bk1, aq[1][1], s1[ni], 0, 0, 0);
    }
    __builtin_amdgcn_s_setprio(0);
    __builtin_amdgcn_s_barrier();                        // Ks reads done block-wide
    stageK(kbn);                                         // K(t+1) -> Ks (hides under SM/PV)
    asm volatile("s_waitcnt vmcnt(4)" ::: "memory");     // my V(t) landed
    __builtin_amdgcn_s_barrier();                        // everyone's V(t) landed

    u32* Ps32 = (u32*)Ps;

    // ---- head 0: two 64-key halves of SM -> PV through the 8 KB Ps.
    {
      float Lh = 0.f;
#pragma unroll
      for (int hf = 0; hf < 2; hf++) {
        const bool mh = (kb + hf * 64 + 63 > qrowW);     // wave-uniform per half
        if (mh) {
#pragma unroll
          for (int nl = 0; nl < 4; nl++) {
            const int ni = hf * 4 + nl;
            const int dlim = qrow - (kb + ni * 16 + kg * 4);
            float p0 = fastexp2(fmaf(s0[ni][0], 0.18033688f, -11.5415603f));
            float p1 = fastexp2(fmaf(s0[ni][1], 0.18033688f, -11.5415603f));
            float p2 = fastexp2(fmaf(s0[ni][2], 0.18033688f, -11.5415603f));
            float p3 = fastexp2(fmaf(s0[ni][3], 0.18033688f, -11.5415603f));
            p0 = (0 <= dlim) ? p0 : 0.f;
            p1 = (1 <= dlim) ? p1 : 0.f;
            p2 = (2 <= dlim) ? p2 : 0.f;
            p3 = (3 <= dlim) ? p3 : 0.f;
            Lh += (p0 + p1) + (p2 + p3);
            bf16x4 w;
            w[0] = (__bf16)p0; w[1] = (__bf16)p1; w[2] = (__bf16)p2; w[3] = (__bf16)p3;
            *(bf16x4*)&Ps32[prow * 32 + ((2 * nl + (kg >> 1)) ^ sx) * 4 + (kg & 1) * 2] = w;
          }
        } else {
#pragma unroll
          for (int nl = 0; nl < 4; nl++) {
            const int ni = hf * 4 + nl;
            float p0 = fastexp2(fmaf(s0[ni][0], 0.18033688f, -11.5415603f));
            float p1 = fastexp2(fmaf(s0[ni][1], 0.18033688f, -11.5415603f));
            float p2 = fastexp2(fmaf(s0[ni][2], 0.18033688f, -11.5415603f));
            float p3 = fastexp2(fmaf(s0[ni][3], 0.18033688f, -11.5415603f));
            Lh += (p0 + p1) + (p2 + p3);
            bf16x4 w;
            w[0] = (__bf16)p0; w[1] = (__bf16)p1; w[2] = (__bf16)p2; w[3] = (__bf16)p3;
            *(bf16x4*)&Ps32[prow * 32 + ((2 * nl + (kg >> 1)) ^ sx) * 4 + (kg & 1) * 2] = w;
          }
        }
        __builtin_amdgcn_s_setprio(1);
#pragma unroll
        for (int k0l = 0; k0l < 64; k0l += 32) {
          const bf16x8 ap = *(const bf16x8*)&Ps[prow * 64 + ((((k0l >> 3) + kg)) ^ sx) * 8];
          const int cgv = ((hf * 64 + k0l) >> 3) + kg;
#pragma unroll
          for (int ni2 = 0; ni2 < 4; ni2++) {
            const bf16x8 bv = *(const bf16x8*)&Vs[(ni2 * 16 + fr) * 128 + ((cgv ^ sx)) * 8];
            o[0][ni2] = __builtin_amdgcn_mfma_f32_16x16x32_bf16(ap, bv, o[0][ni2], 0, 0, 0);
          }
        }
        __builtin_amdgcn_s_setprio(0);
      }
      L[0] += Lh;
    }

    // ---- head 1: same two-half pipeline (SM VALU overlaps head-0's PV tail).
    {
      float Lh = 0.f;
#pragma unroll
      for (int hf = 0; hf < 2; hf++) {
        const bool mh = (kb + hf * 64 + 63 > qrowW);
        if (mh) {
#pragma unroll
          for (int nl = 0; nl < 4; nl++) {
            const int ni = hf * 4 + nl;
            const int dlim = qrow - (kb + ni * 16 + kg * 4);
            float p0 = fastexp2(fmaf(s1[ni][0], 0.18033688f, -11.5415603f));
            float p1 = fastexp2(fmaf(s1[ni][1], 0.18033688f, -11.5415603f));
            float p2 = fastexp2(fmaf(s1[ni][2], 0.18033688f, -11.5415603f));
            float p3 = fastexp2(fmaf(s1[ni][3], 0.18033688f, -11.5415603f));
            p0 = (0 <= dlim) ? p0 : 0.f;
            p1 = (1 <= dlim) ? p1 : 0.f;
            p2 = (2 <= dlim) ? p2 : 0.f;
            p3 = (3 <= dlim) ? p3 : 0.f;
            Lh += (p0 + p1) + (p2 + p3);
            bf16x4 w;
            w[0] = (__bf16)p0; w[1] = (__bf16)p1; w[2] = (__bf16)p2; w[3] = (__bf16)p3;
            *(bf16x4*)&Ps32[prow * 32 + ((2 * nl + (kg >> 1)) ^ sx) * 4 + (kg & 1) * 2] = w;
          }
        } else {
#pragma unroll
          for (int nl = 0; nl < 4; nl++) {
            const int ni = hf * 4 + nl;
            float p0 = fastexp2(fmaf(s1[ni][0], 0.18033688f, -11.5415603f));
            float p1 = fastexp2(fmaf(s1[ni][1], 0.18033688f, -11.5415603f));
            float p2 = fastexp2(fmaf(s1[ni][2], 0.18033688f, -11.5415603f));
            float p3 = fastexp2(fmaf(s1[ni][3], 0.18033688f, -11.5415603f));
            Lh += (p0 + p1) + (p2 + p3);
            bf16x4 w;
            w[0] = (__bf16)p0; w[1] = (__bf16)p1; w[2] = (__bf16)p2; w[3] = (__bf16)p3;
            *(bf16x4*)&Ps32[prow * 32 + ((2 * nl + (kg >> 1)) ^ sx) * 4 + (kg & 1) * 2] = w;
          }
        }
        __builtin_amdgcn_s_setprio(1);
#pragma unroll
        for (int k0l = 0; k0l < 64; k0l += 32) {
          const bf16x8 ap = *(const bf16x8*)&Ps[prow * 64 + ((((k0l >> 3) + kg)) ^ sx) * 8];
          const int cgv = ((hf * 64 + k0l) >> 3) + kg;
#pragma unroll
          for (int ni2 = 0; ni2 < 4; ni2++) {
            const bf16x8 bv = *(const bf16x8*)&Vs[(ni2 * 16 + fr) * 128 + ((cgv ^ sx)) * 8];
            o[1][ni2] = __builtin_amdgcn_mfma_f32_16x16x32_bf16(ap, bv, o[1][ni2], 0, 0, 0);
          }
        }
        __builtin_amdgcn_s_setprio(0);
      }
      L[1] += Lh;
    }
    __builtin_amdgcn_s_barrier();                        // Vs/Ps reads done block-wide
    stageV(kbn);                                         // V(t+1) -> Vs (hides under next QK)
  }
  // Drain in-flight LDS writes before the block can exit (LDS is reallocated).
  asm volatile("s_waitcnt vmcnt(0)" ::: "memory");

#pragma unroll
  for (int hh = 0; hh < 2; hh++) {
    float Lh = L[hh];
    Lh += __shfl_xor(Lh, 16, 64);
    Lh += __shfl_xor(Lh, 32, 64);
    const int h = h0 + hh;
    const int pbase = (h * 80 + c) * 4096;
#pragma unroll
    for (int ni = 0; ni < 4; ni++)
#pragma unroll
      for (int r = 0; r < 4; r++)
        part[pbase + (wave * 16 + kg * 4 + r) * 64 + ni * 16 + fr] = f2bf(o[hh][ni][r]);
    if (lane < 16) ml[(h * 80 + c) * 64 + wave * 16 + fr] = Lh;
  }
}

// ---- Split-KV pass 2: plain sums (shared fixed max); fuse sigmoid gating.
// Vectorized: each thread owns 4 cols (ushort4) x 4 rows -> 8 B/lane memory ops.
__global__ __launch_bounds__(256) void k_attn_comb(
    const u16* __restrict__ part, const float* __restrict__ ml,
    const u16* __restrict__ qkvg, u16* __restrict__ aout)
{
  const int qt = blockIdx.x, h = blockIdx.y;
  int cb, nch;
  if (qt < 8)       { cb = qt;               nch = 1; }
  else if (qt < 16) { cb = 8 + 2 * (qt - 8);  nch = 2; }
  else if (qt < 24) { cb = 24 + 3 * (qt - 16); nch = 3; }
  else              { cb = 48 + 4 * (qt - 24); nch = 4; }
  const int c4 = (threadIdx.x & 15) * 4;     // column base within the head
  const int rg = threadIdx.x >> 4;           // 0..15
  const float LOG2E = 1.44269504f;
#pragma unroll
  for (int rr = 0; rr < 4; rr++) {
    const int rl = rr * 16 + rg;
    const int row = qt * 64 + rl;
    float L = 0.f, o0 = 0.f, o1 = 0.f, o2 = 0.f, o3 = 0.f;
    for (int cc = 0; cc < nch; cc++) {
      L += ml[(h * 80 + cb + cc) * 64 + rl];
      const ushort4 pv = *(const ushort4*)&part[(size_t)(h * 80 + cb + cc) * 4096 + rl * 64 + c4];
      o0 += bf2f(pv.x); o1 += bf2f(pv.y); o2 += bf2f(pv.z); o3 += bf2f(pv.w);
    }
    const ushort4 gv = *(const ushort4*)&qkvg[(size_t)row * 5120 + 3072 + h * 64 + c4];
    const float inv = 1.0f / L;
    const float s0 = 1.0f / (1.0f + fastexp2(-bf2f(gv.x) * LOG2E));
    const float s1 = 1.0f / (1.0f + fastexp2(-bf2f(gv.y) * LOG2E));
    const float s2 = 1.0f / (1.0f + fastexp2(-bf2f(gv.z) * LOG2E));
    const float s3 = 1.0f / (1.0f + fastexp2(-bf2f(gv.w) * LOG2E));
    ushort4 ov;
    ov.x = f2bf(o0 * inv * s0);
    ov.y = f2bf(o1 * inv * s1);
    ov.z = f2bf(o2 * inv * s2);
    ov.w = f2bf(o3 * inv * s3);
    *(ushort4*)&aout[(size_t)row * 2048 + h * 64 + c4] = ov;
  }
}

extern "C" void kernel_launch(void* const* d_in, const int* in_sizes, int n_in,
                              void* d_out, int out_size, void* d_ws, size_t ws_size,
                              hipStream_t stream)
{
  const float* x  = (const float*)d_in[0];
  const float* cs = (const float*)d_in[1];
  const float* sn = (const float*)d_in[2];
  const float* wq = (const float*)d_in[3];
  const float* wk = (const float*)d_in[4];
  const float* wv = (const float*)d_in[5];
  const float* wo = (const float*)d_in[6];
  const float* wg = (const float*)d_in[7];
  const float* qn = (const float*)d_in[8];
  const float* kn = (const float*)d_in[9];
  float* out = (float*)d_out;

  u16* xb   = (u16*)d_ws;                      // 4M elems  (cast region, dead after qkvg gemm)
  u16* wqb  = xb  + (size_t)4194304;           // 4M
  u16* wkb  = wqb + (size_t)4194304;           // 1M
  u16* wvb  = wkb + (size_t)1048576;           // 1M
  u16* wgb  = wvb + (size_t)1048576;           // 4M
  u16* wob  = wgb + (size_t)4194304;           // 4M  (alive until final gemm)
  u16* qkvg = wob + (size_t)4194304;           // 2048*5120
  u16* vt   = qkvg + (size_t)2048 * 5120;      // 512*2048
  u16* aws  = vt   + (size_t)512 * 2048;       // 2048*2048

  u16*   part = xb;                                     // 32*80*4096 bf16 = 21 MB
  float* ml   = (float*)(xb + (size_t)32 * 80 * 4096);  // 32*80*64 fp32 = 0.64 MB

  k_cast<<<dim3(18432), 256, 0, stream>>>(x, xb, wq, wqb, wk, wkb, wv, wvb, wo, wob, wg, wgb);
  k_gemm_qkvg<<<dim3(16, 40), 256, 0, stream>>>(xb, wqb, wkb, wvb, wgb, qkvg);
  k_prep<<<dim3(10240 + 256), 256, 0, stream>>>(qkvg, cs, sn, qn, kn, vt);
  k_attn_part<<<dim3(80, 16), 256, 0, stream>>>(qkvg, vt, part, ml);
  k_attn_comb<<<dim3(32, 32), 256, 0, stream>>>(part, ml, qkvg, aws);
  k_gemm_out<<<dim3(16, 32), 256, 0, stream>>>(aws, wob, out);
}